// Round 4
// baseline (6996.967 us; speedup 1.0000x reference)
//
#include <hip/hip_runtime.h>
#include <math.h>

// Problem constants (fixed by setup_inputs): B=32, N=512, Ds=1024, Dt=2048
// TEMP=0.07 ALPHA=0.5 OT_EPS=0.1 (1/eps=10) OT_ITERS=20 KD=1
// dims [256,512,1024], weights [1,1,1]

__device__ __forceinline__ float wredsum(float x) {
#pragma unroll
  for (int o = 1; o < 64; o <<= 1) x += __shfl_xor(x, o);
  return x;
}
__device__ __forceinline__ float wredmax(float x) {
#pragma unroll
  for (int o = 1; o < 64; o <<= 1) x = fmaxf(x, __shfl_xor(x, o));
  return x;
}

// ---------------- row norms (wave per row) ----------------
__global__ __launch_bounds__(256) void rownorm_k(const float* __restrict__ X,
                                                 float* __restrict__ nrm,
                                                 float* __restrict__ rinv, int D) {
  int w = threadIdx.x >> 6, l = threadIdx.x & 63;
  long row = (long)blockIdx.x * 4 + w;
  const float4* Xr = reinterpret_cast<const float4*>(X + row * D);
  float s = 0.f;
  for (int idx = l; idx < (D >> 2); idx += 64) {
    float4 v = Xr[idx];
    s += v.x * v.x + v.y * v.y + v.z * v.z + v.w * v.w;
  }
  s = wredsum(s);
  if (l == 0) {
    float n = sqrtf(s);
    nrm[row] = n;
    rinv[row] = 1.f / fmaxf(n, 1e-12f);
  }
}

// ---------------- saliency: softmax over N=512 per batch ----------------
__global__ __launch_bounds__(256) void saliency_k(const float* __restrict__ nrm,
                                                  float* __restrict__ mu,
                                                  float* __restrict__ logmu) {
  __shared__ float sd[256];
  int b = blockIdx.x, t = threadIdx.x;
  float a = nrm[b * 512 + t], c = nrm[b * 512 + 256 + t];
  sd[t] = fmaxf(a, c);
  __syncthreads();
  for (int o = 128; o > 0; o >>= 1) { if (t < o) sd[t] = fmaxf(sd[t], sd[t + o]); __syncthreads(); }
  float M = sd[0];
  __syncthreads();
  float e1 = __expf(a - M), e2 = __expf(c - M);
  sd[t] = e1 + e2;
  __syncthreads();
  for (int o = 128; o > 0; o >>= 1) { if (t < o) sd[t] += sd[t + o]; __syncthreads(); }
  float S = sd[0];
  float m1 = e1 / S, m2 = e2 / S;
  mu[b * 512 + t] = m1;
  mu[b * 512 + 256 + t] = m2;
  logmu[b * 512 + t] = logf(m1 + 1e-8f);
  logmu[b * 512 + 256 + t] = logf(m2 + 1e-8f);
}

// ---------------- GEMM NT: C[b] = A[b] (Na x K) @ B[b]^T (Nb x K) ----------------
// EPI 0: C = 1 - acc*sa[i]*sb[j]   (cosine distance, norms folded as reciprocals)
// EPI 1: mapped = acc*sb[j]; p += (Cs - mapped)^2 * mu[i]*mu[j]; atomicAdd (no C write)
template <int EPI>
__global__ __launch_bounds__(256) void gemm_nt_k(
    const float* __restrict__ A, const float* __restrict__ Bm, float* __restrict__ C,
    const float* __restrict__ sa, const float* __restrict__ sb,
    const float* __restrict__ Csm, const float* __restrict__ muv, float* __restrict__ accp,
    int K, long strA, long strB, long strC) {
  __shared__ float As[16][132];
  __shared__ float Bs[16][132];
  __shared__ float red[256];
  int b = blockIdx.z;
  const float* Ab = A + (long)b * strA;
  const float* Bb = Bm + (long)b * strB;
  int i0 = blockIdx.y * 128, j0 = blockIdx.x * 128;
  int Nb = gridDim.x * 128;
  int t = threadIdx.x, tx = t & 15, ty = t >> 4;
  float acc[8][8];
#pragma unroll
  for (int i = 0; i < 8; i++)
#pragma unroll
    for (int j = 0; j < 8; j++) acc[i][j] = 0.f;
  int lr = t >> 2, lc = (t & 3) * 4;
  for (int k0 = 0; k0 < K; k0 += 16) {
#pragma unroll
    for (int h = 0; h < 2; ++h) {
      int r = lr + h * 64;
      float4 va = *reinterpret_cast<const float4*>(Ab + (long)(i0 + r) * K + k0 + lc);
      As[lc + 0][r] = va.x; As[lc + 1][r] = va.y; As[lc + 2][r] = va.z; As[lc + 3][r] = va.w;
      float4 vb = *reinterpret_cast<const float4*>(Bb + (long)(j0 + r) * K + k0 + lc);
      Bs[lc + 0][r] = vb.x; Bs[lc + 1][r] = vb.y; Bs[lc + 2][r] = vb.z; Bs[lc + 3][r] = vb.w;
    }
    __syncthreads();
#pragma unroll
    for (int kk = 0; kk < 16; ++kk) {
      const float4* Ap = reinterpret_cast<const float4*>(&As[kk][ty * 8]);
      const float4* Bp = reinterpret_cast<const float4*>(&Bs[kk][tx * 8]);
      float4 a0 = Ap[0], a1 = Ap[1], b0 = Bp[0], b1 = Bp[1];
      float a8[8] = {a0.x, a0.y, a0.z, a0.w, a1.x, a1.y, a1.z, a1.w};
      float b8[8] = {b0.x, b0.y, b0.z, b0.w, b1.x, b1.y, b1.z, b1.w};
#pragma unroll
      for (int i = 0; i < 8; i++)
#pragma unroll
        for (int j = 0; j < 8; j++) acc[i][j] = fmaf(a8[i], b8[j], acc[i][j]);
    }
    __syncthreads();
  }
  if (EPI == 0) {
    float rsa[8], rsb[8];
#pragma unroll
    for (int i = 0; i < 8; i++) rsa[i] = sa[b * 512 + i0 + ty * 8 + i];
#pragma unroll
    for (int j = 0; j < 8; j++) rsb[j] = sb[b * 512 + j0 + tx * 8 + j];
#pragma unroll
    for (int i = 0; i < 8; i++) {
      float* Cr = C + (long)b * strC + (long)(i0 + ty * 8 + i) * Nb + j0 + tx * 8;
      float4 v0, v1;
      v0.x = 1.f - acc[i][0] * rsa[i] * rsb[0];
      v0.y = 1.f - acc[i][1] * rsa[i] * rsb[1];
      v0.z = 1.f - acc[i][2] * rsa[i] * rsb[2];
      v0.w = 1.f - acc[i][3] * rsa[i] * rsb[3];
      v1.x = 1.f - acc[i][4] * rsa[i] * rsb[4];
      v1.y = 1.f - acc[i][5] * rsa[i] * rsb[5];
      v1.z = 1.f - acc[i][6] * rsa[i] * rsb[6];
      v1.w = 1.f - acc[i][7] * rsa[i] * rsb[7];
      *reinterpret_cast<float4*>(Cr) = v0;
      *reinterpret_cast<float4*>(Cr + 4) = v1;
    }
  } else {
    float rsb[8], mub[8], mua[8];
#pragma unroll
    for (int j = 0; j < 8; j++) {
      rsb[j] = sb[b * 512 + j0 + tx * 8 + j];
      mub[j] = muv[b * 512 + j0 + tx * 8 + j];
    }
#pragma unroll
    for (int i = 0; i < 8; i++) mua[i] = muv[b * 512 + i0 + ty * 8 + i];
    float p = 0.f;
#pragma unroll
    for (int i = 0; i < 8; i++) {
      const float* Cr = Csm + (long)b * strC + (long)(i0 + ty * 8 + i) * Nb + j0 + tx * 8;
#pragma unroll
      for (int j = 0; j < 8; j++) {
        float mapped = acc[i][j] * rsb[j];
        float d = Cr[j] - mapped;
        p += d * d * mua[i] * mub[j];
      }
    }
    red[t] = p;
    __syncthreads();
    for (int o = 128; o > 0; o >>= 1) { if (t < o) red[t] += red[t + o]; __syncthreads(); }
    if (t == 0) atomicAdd(accp, red[0]);
  }
}

// ---------------- GEMM NN: C[b] = A[b] (M x K) @ B[b] (K x N) ----------------
// EPI 0: C = acc + bias[j]          (projection, non-batched)
// EPI 1: C = acc * rowscale[b*512+i] (Gamma_norm @ Ct)
template <int EPI>
__global__ __launch_bounds__(256) void gemm_nn_k(
    const float* __restrict__ A, const float* __restrict__ Bm, float* __restrict__ C,
    const float* __restrict__ aux, int K, int N, long strA, long strB, long strC) {
  __shared__ float As[16][132];
  __shared__ float Bs[16][132];
  int b = blockIdx.z;
  const float* Ab = A + (long)b * strA;
  const float* Bb = Bm + (long)b * strB;
  int i0 = blockIdx.y * 128, j0 = blockIdx.x * 128;
  int t = threadIdx.x, tx = t & 15, ty = t >> 4;
  float acc[8][8];
#pragma unroll
  for (int i = 0; i < 8; i++)
#pragma unroll
    for (int j = 0; j < 8; j++) acc[i][j] = 0.f;
  int lr = t >> 2, lc = (t & 3) * 4;
  int kr = t >> 4, jc = (t & 15) * 8;
  for (int k0 = 0; k0 < K; k0 += 16) {
#pragma unroll
    for (int h = 0; h < 2; ++h) {
      int r = lr + h * 64;
      float4 va = *reinterpret_cast<const float4*>(Ab + (long)(i0 + r) * K + k0 + lc);
      As[lc + 0][r] = va.x; As[lc + 1][r] = va.y; As[lc + 2][r] = va.z; As[lc + 3][r] = va.w;
    }
    float4 vb0 = *reinterpret_cast<const float4*>(Bb + (long)(k0 + kr) * N + j0 + jc);
    float4 vb1 = *reinterpret_cast<const float4*>(Bb + (long)(k0 + kr) * N + j0 + jc + 4);
    *reinterpret_cast<float4*>(&Bs[kr][jc]) = vb0;
    *reinterpret_cast<float4*>(&Bs[kr][jc + 4]) = vb1;
    __syncthreads();
#pragma unroll
    for (int kk = 0; kk < 16; ++kk) {
      const float4* Ap = reinterpret_cast<const float4*>(&As[kk][ty * 8]);
      const float4* Bp = reinterpret_cast<const float4*>(&Bs[kk][tx * 8]);
      float4 a0 = Ap[0], a1 = Ap[1], b0 = Bp[0], b1 = Bp[1];
      float a8[8] = {a0.x, a0.y, a0.z, a0.w, a1.x, a1.y, a1.z, a1.w};
      float b8[8] = {b0.x, b0.y, b0.z, b0.w, b1.x, b1.y, b1.z, b1.w};
#pragma unroll
      for (int i = 0; i < 8; i++)
#pragma unroll
        for (int j = 0; j < 8; j++) acc[i][j] = fmaf(a8[i], b8[j], acc[i][j]);
    }
    __syncthreads();
  }
  if (EPI == 0) {
    float bj[8];
#pragma unroll
    for (int j = 0; j < 8; j++) bj[j] = aux[j0 + tx * 8 + j];
#pragma unroll
    for (int i = 0; i < 8; i++) {
      float* Cr = C + (long)b * strC + (long)(i0 + ty * 8 + i) * N + j0 + tx * 8;
      float4 v0, v1;
      v0.x = acc[i][0] + bj[0]; v0.y = acc[i][1] + bj[1];
      v0.z = acc[i][2] + bj[2]; v0.w = acc[i][3] + bj[3];
      v1.x = acc[i][4] + bj[4]; v1.y = acc[i][5] + bj[5];
      v1.z = acc[i][6] + bj[6]; v1.w = acc[i][7] + bj[7];
      *reinterpret_cast<float4*>(Cr) = v0;
      *reinterpret_cast<float4*>(Cr + 4) = v1;
    }
  } else {
#pragma unroll
    for (int i = 0; i < 8; i++) {
      float sc = aux[b * 512 + i0 + ty * 8 + i];
      float* Cr = C + (long)b * strC + (long)(i0 + ty * 8 + i) * N + j0 + tx * 8;
      float4 v0, v1;
      v0.x = acc[i][0] * sc; v0.y = acc[i][1] * sc;
      v0.z = acc[i][2] * sc; v0.w = acc[i][3] * sc;
      v1.x = acc[i][4] * sc; v1.y = acc[i][5] * sc;
      v1.z = acc[i][6] * sc; v1.w = acc[i][7] * sc;
      *reinterpret_cast<float4*>(Cr) = v0;
      *reinterpret_cast<float4*>(Cr + 4) = v1;
    }
  }
}

// ---------------- Sinkhorn (log domain), logK = -10*M ----------------
__global__ __launch_bounds__(256) void sink_u_k(const float* __restrict__ Mm,
                                                const float* __restrict__ v,
                                                const float* __restrict__ logmu,
                                                float* __restrict__ u) {
  int b = blockIdx.y;
  int w = threadIdx.x >> 6, l = threadIdx.x & 63;
  int i = blockIdx.x * 4 + w;
  const float* Mr = Mm + ((long)b * 512 + i) * 512;
  const float* vb = v + b * 512;
  float m = -INFINITY, s = 0.f;
#pragma unroll
  for (int jj = 0; jj < 8; ++jj) {
    int j = jj * 64 + l;
    float val = fmaf(-10.f, Mr[j], vb[j]);
    if (val > m) { s = s * __expf(m - val) + 1.f; m = val; }
    else s += __expf(val - m);
  }
#pragma unroll
  for (int o = 1; o < 64; o <<= 1) {
    float m2 = __shfl_xor(m, o), s2 = __shfl_xor(s, o);
    float nm = fmaxf(m, m2);
    s = s * __expf(m - nm) + s2 * __expf(m2 - nm);
    m = nm;
  }
  if (l == 0) u[b * 512 + i] = logmu[b * 512 + i] - (m + logf(s));
}

__global__ __launch_bounds__(256) void sink_va_k(const float* __restrict__ Mm,
                                                 const float* __restrict__ u,
                                                 float* __restrict__ pm, float* __restrict__ ps) {
  int b = blockIdx.z, ic = blockIdx.y;
  int j = blockIdx.x * 256 + threadIdx.x;
  const float* ub = u + b * 512 + ic * 128;
  const float* Mp = Mm + ((long)b * 512 + ic * 128) * 512 + j;
  float m = -INFINITY, s = 0.f;
  for (int ii = 0; ii < 128; ++ii) {
    float val = fmaf(-10.f, Mp[(long)ii * 512], ub[ii]);
    if (val > m) { s = s * __expf(m - val) + 1.f; m = val; }
    else s += __expf(val - m);
  }
  pm[((b * 512 + j) << 2) + ic] = m;
  ps[((b * 512 + j) << 2) + ic] = s;
}

__global__ __launch_bounds__(256) void sink_vb_k(const float* __restrict__ pm,
                                                 const float* __restrict__ ps,
                                                 const float* __restrict__ lognu,
                                                 float* __restrict__ v) {
  int b = blockIdx.y;
  int j = blockIdx.x * 256 + threadIdx.x;
  float m = -INFINITY, s = 0.f;
#pragma unroll
  for (int ic = 0; ic < 4; ++ic) {
    float m2 = pm[((b * 512 + j) << 2) + ic], s2 = ps[((b * 512 + j) << 2) + ic];
    float nm = fmaxf(m, m2);
    s = s * __expf(m - nm) + s2 * __expf(m2 - nm);
    m = nm;
  }
  v[b * 512 + j] = lognu[b * 512 + j] - (m + logf(s));
}

// ---------------- Gamma = exp(u + logK + v), rowsum, feat partials ----------------
__global__ __launch_bounds__(256) void gamma_k(const float* __restrict__ Mm,
                                               const float* __restrict__ u,
                                               const float* __restrict__ v,
                                               float* __restrict__ G,
                                               float* __restrict__ invrs,
                                               float* __restrict__ feat_row) {
  int b = blockIdx.y;
  int w = threadIdx.x >> 6, l = threadIdx.x & 63;
  int i = blockIdx.x * 4 + w;
  const float* Mr = Mm + ((long)b * 512 + i) * 512;
  float* Gr = G + ((long)b * 512 + i) * 512;
  const float* vb = v + b * 512;
  float ui = u[b * 512 + i];
  float rs = 0.f, fp = 0.f;
#pragma unroll
  for (int jj = 0; jj < 8; ++jj) {
    int j = jj * 64 + l;
    float mm = Mr[j];
    float g = __expf(fmaf(-10.f, mm, ui + vb[j]));
    Gr[j] = g;
    rs += g;
    fp = fmaf(mm, g, fp);
  }
  rs = wredsum(rs);
  fp = wredsum(fp);
  if (l == 0) {
    invrs[b * 512 + i] = 1.f / (rs + 1e-8f);
    feat_row[b * 512 + i] = fp;
  }
}

__global__ __launch_bounds__(256) void reduce_sum_k(const float* __restrict__ x, int n,
                                                    float* __restrict__ out) {
  __shared__ float sd[256];
  int t = threadIdx.x;
  float s = 0.f;
  for (int i = t; i < n; i += 256) s += x[i];
  sd[t] = s;
  __syncthreads();
  for (int o = 128; o > 0; o >>= 1) { if (t < o) sd[t] += sd[t + o]; __syncthreads(); }
  if (t == 0) atomicAdd(out, sd[0]);
}

// ---------------- Contrastive (tiny) ----------------
__global__ __launch_bounds__(256) void cnorm_k(const float* __restrict__ q,
                                               const float* __restrict__ p,
                                               float* __restrict__ rqp) {
  __shared__ float sd[3][256];
  int mat = blockIdx.x >> 5, row = blockIdx.x & 31, t = threadIdx.x;
  const float* X = (mat ? p : q) + row * 1024;
  float x0 = X[t], x1 = X[256 + t], x2 = X[512 + t], x3 = X[768 + t];
  sd[0][t] = x0 * x0;
  sd[1][t] = x1 * x1;
  sd[2][t] = x2 * x2 + x3 * x3;
  __syncthreads();
  for (int o = 128; o > 0; o >>= 1) {
    if (t < o) { sd[0][t] += sd[0][t + o]; sd[1][t] += sd[1][t + o]; sd[2][t] += sd[2][t + o]; }
    __syncthreads();
  }
  if (t == 0) {
    float c1 = sd[0][0], c2 = c1 + sd[1][0], c3 = c2 + sd[2][0];
    rqp[(mat * 32 + row) * 3 + 0] = 1.f / fmaxf(sqrtf(c1), 1e-12f);
    rqp[(mat * 32 + row) * 3 + 1] = 1.f / fmaxf(sqrtf(c2), 1e-12f);
    rqp[(mat * 32 + row) * 3 + 2] = 1.f / fmaxf(sqrtf(c3), 1e-12f);
  }
}

__global__ __launch_bounds__(256) void cscore_k(const float* __restrict__ q,
                                                const float* __restrict__ p,
                                                float* __restrict__ sc3) {
  int i = blockIdx.x;
  int w = threadIdx.x >> 6, l = threadIdx.x & 63;
  const float* qi = q + i * 1024;
  for (int j8 = 0; j8 < 8; ++j8) {
    int j = j8 * 4 + w;
    const float* pj = p + j * 1024;
    float s1 = 0.f, s2 = 0.f, s3 = 0.f;
#pragma unroll
    for (int it = 0; it < 4; ++it) { int e = it * 64 + l; s1 = fmaf(qi[e], pj[e], s1); }
#pragma unroll
    for (int it = 4; it < 8; ++it) { int e = it * 64 + l; s2 = fmaf(qi[e], pj[e], s2); }
#pragma unroll
    for (int it = 8; it < 16; ++it) { int e = it * 64 + l; s3 = fmaf(qi[e], pj[e], s3); }
    s1 = wredsum(s1); s2 = wredsum(s2); s3 = wredsum(s3);
    if (l == 0) {
      sc3[(0 * 32 + i) * 32 + j] = s1;
      sc3[(1 * 32 + i) * 32 + j] = s1 + s2;
      sc3[(2 * 32 + i) * 32 + j] = s1 + s2 + s3;
    }
  }
}

__global__ void closs_k(const float* __restrict__ sc3, const float* __restrict__ rqp,
                        float* __restrict__ acc) {
  int i = blockIdx.x, d = blockIdx.y, j = threadIdx.x;  // block = 64 (1 wave)
  float sc = -INFINITY;
  if (j < 32)
    sc = sc3[(d * 32 + i) * 32 + j] * rqp[i * 3 + d] * rqp[(32 + j) * 3 + d] * (1.f / 0.07f);
  float mx = wredmax(sc);
  float e = (j < 32) ? __expf(sc - mx) : 0.f;
  float S = wredsum(e);
  float lse = mx + logf(S);
  float diag = __shfl(sc, i);
  if (j == 0) atomicAdd(acc, (lse - diag) * (1.f / 32.f));
}

__global__ void final_k(const float* __restrict__ acc, float* __restrict__ out) {
  float contr = acc[0];
  float lq = 0.5f * (acc[1] / 32.f) + 0.5f * (acc[2] / 32.f);
  float lp = 0.5f * (acc[3] / 32.f) + 0.5f * (acc[4] / 32.f);
  out[0] = contr + 0.5f * (lq + lp);
}

extern "C" void kernel_launch(void* const* d_in, const int* in_sizes, int n_in,
                              void* d_out, int out_size, void* d_ws, size_t ws_size,
                              hipStream_t stream) {
  const float* s_q_reps = (const float*)d_in[0];
  const float* s_p_reps = (const float*)d_in[1];
  const float* s_q_states = (const float*)d_in[2];
  const float* s_p_states = (const float*)d_in[3];
  const float* t_q_states = (const float*)d_in[4];
  const float* t_p_states = (const float*)d_in[5];
  const float* Wp = (const float*)d_in[6];
  const float* bp = (const float*)d_in[7];
  float* ws = (float*)d_ws;

  const long szP = 33554432L;   // 32*512*2048
  const long szNN = 8388608L;   // 32*512*512
  float* P = ws;                // projected z_s (dead after M) ...
  float* G = ws;                // ... Gamma aliases P[0 : szNN)
  float* T1 = ws + szNN;        // T1 aliases P[szNN : 2*szNN)
  float* Cs = ws + szP;
  float* Ct = Cs + szNN;
  float* Mm = Ct + szNN;
  float* sm = Mm + szNN;
  float* nrm_s = sm; sm += 16384;
  float* rinv_s = sm; sm += 16384;
  float* nrm_t = sm; sm += 16384;
  float* rinv_t = sm; sm += 16384;
  float* nrm_p = sm; sm += 16384;
  float* rinv_p = sm; sm += 16384;
  float* mu = sm; sm += 16384;
  float* logmu = sm; sm += 16384;
  float* nu = sm; sm += 16384;
  float* lognu = sm; sm += 16384;
  float* uu = sm; sm += 16384;
  float* vv = sm; sm += 16384;
  float* invrs = sm; sm += 16384;
  float* feat_row = sm; sm += 16384;
  float* pm = sm; sm += 65536;
  float* ps = sm; sm += 65536;
  float* sc3 = sm; sm += 3072;
  float* rqp = sm; sm += 192;
  float* acc = sm; sm += 16;

  hipMemsetAsync(acc, 0, 16 * sizeof(float), stream);

  // ---- contrastive (matryoshka dims 256/512/1024, weights 1) ----
  cnorm_k<<<64, 256, 0, stream>>>(s_q_reps, s_p_reps, rqp);
  cscore_k<<<32, 256, 0, stream>>>(s_q_reps, s_p_reps, sc3);
  closs_k<<<dim3(32, 3), 64, 0, stream>>>(sc3, rqp, acc);

  // ---- FGW for (q) then (p), reusing all buffers ----
  for (int side = 0; side < 2; ++side) {
    const float* zs = side ? s_p_states : s_q_states;
    const float* zt = side ? t_p_states : t_q_states;
    float* featAcc = acc + 1 + side * 2;
    float* structAcc = acc + 2 + side * 2;

    rownorm_k<<<4096, 256, 0, stream>>>(zs, nrm_s, rinv_s, 1024);
    rownorm_k<<<4096, 256, 0, stream>>>(zt, nrm_t, rinv_t, 2048);
    saliency_k<<<32, 256, 0, stream>>>(nrm_s, mu, logmu);
    saliency_k<<<32, 256, 0, stream>>>(nrm_t, nu, lognu);

    // P = zs @ W + b  (16384 x 2048, K=1024)
    gemm_nn_k<0><<<dim3(16, 128, 1), 256, 0, stream>>>(zs, Wp, P, bp, 1024, 2048, 0, 0, 0);
    rownorm_k<<<4096, 256, 0, stream>>>(P, nrm_p, rinv_p, 2048);

    // Cs = 1 - cos(zs, zs); Ct = 1 - cos(zt, zt); M = 1 - cos(P, zt)
    gemm_nt_k<0><<<dim3(4, 4, 32), 256, 0, stream>>>(zs, zs, Cs, rinv_s, rinv_s, nullptr, nullptr,
                                                     nullptr, 1024, 512L * 1024, 512L * 1024,
                                                     512L * 512);
    gemm_nt_k<0><<<dim3(4, 4, 32), 256, 0, stream>>>(zt, zt, Ct, rinv_t, rinv_t, nullptr, nullptr,
                                                     nullptr, 2048, 512L * 2048, 512L * 2048,
                                                     512L * 512);
    gemm_nt_k<0><<<dim3(4, 4, 32), 256, 0, stream>>>(P, zt, Mm, rinv_p, rinv_t, nullptr, nullptr,
                                                     nullptr, 2048, 512L * 2048, 512L * 2048,
                                                     512L * 512);

    hipMemsetAsync(uu, 0, 16384 * sizeof(float), stream);
    hipMemsetAsync(vv, 0, 16384 * sizeof(float), stream);
    for (int it = 0; it < 20; ++it) {
      sink_u_k<<<dim3(128, 32), 256, 0, stream>>>(Mm, vv, logmu, uu);
      sink_va_k<<<dim3(2, 4, 32), 256, 0, stream>>>(Mm, uu, pm, ps);
      sink_vb_k<<<dim3(2, 32), 256, 0, stream>>>(pm, ps, lognu, vv);
    }
    gamma_k<<<dim3(128, 32), 256, 0, stream>>>(Mm, uu, vv, G, invrs, feat_row);
    reduce_sum_k<<<1, 256, 0, stream>>>(feat_row, 16384, featAcc);

    // T1 = Gamma_norm @ Ct ; struct loss fused into T1 @ Gamma_norm^T epilogue
    gemm_nn_k<1><<<dim3(4, 4, 32), 256, 0, stream>>>(G, Ct, T1, invrs, 512, 512, 512L * 512,
                                                     512L * 512, 512L * 512);
    gemm_nt_k<1><<<dim3(4, 4, 32), 256, 0, stream>>>(T1, G, nullptr, mu, invrs, Cs, mu, structAcc,
                                                     512, 512L * 512, 512L * 512, 512L * 512);
  }

  final_k<<<1, 1, 0, stream>>>(acc, (float*)d_out);
}

// Round 5
// 3293.813 us; speedup vs baseline: 2.1243x; 2.1243x over previous
//
#include <hip/hip_runtime.h>
#include <math.h>

// B=32, N=512, Ds=1024, Dt=2048; TEMP=.07 ALPHA=.5 OT_EPS=.1 ITERS=20
typedef __attribute__((ext_vector_type(8))) short short8;
typedef __attribute__((ext_vector_type(4))) float f32x4;

__device__ __forceinline__ float wredsum(float x) {
#pragma unroll
  for (int o = 1; o < 64; o <<= 1) x += __shfl_xor(x, o);
  return x;
}
__device__ __forceinline__ float wredmax(float x) {
#pragma unroll
  for (int o = 1; o < 64; o <<= 1) x = fmaxf(x, __shfl_xor(x, o));
  return x;
}
__device__ __forceinline__ unsigned short f2b(float x) {
  unsigned u = __float_as_uint(x);
  u += 0x7fffu + ((u >> 16) & 1u);
  return (unsigned short)(u >> 16);
}
__device__ __forceinline__ float b2f(unsigned short b) {
  return __uint_as_float(((unsigned)b) << 16);
}

// ---------------- f32 -> bf16 convert (float4 per thread, exact grid) ----------------
__global__ __launch_bounds__(256) void cvt_k(const float* __restrict__ x,
                                             unsigned short* __restrict__ y) {
  long i = (long)blockIdx.x * 256 + threadIdx.x;
  float4 v = reinterpret_cast<const float4*>(x)[i];
  ushort4 o;
  o.x = f2b(v.x); o.y = f2b(v.y); o.z = f2b(v.z); o.w = f2b(v.w);
  reinterpret_cast<ushort4*>(y)[i] = o;
}

// ---------------- W[1024][2048] -> Wt bf16 [2048][1024] ----------------
__global__ __launch_bounds__(256) void wt_k(const float* __restrict__ W,
                                            unsigned short* __restrict__ Wt) {
  __shared__ float t[32][33];
  int n0 = blockIdx.x * 32, k0 = blockIdx.y * 32;
  int tx = threadIdx.x & 31, ty = threadIdx.x >> 5;
  for (int r = ty; r < 32; r += 8) t[r][tx] = W[(long)(k0 + r) * 2048 + n0 + tx];
  __syncthreads();
  for (int r = ty; r < 32; r += 8) Wt[(long)(n0 + r) * 1024 + k0 + tx] = f2b(t[tx][r]);
}

// ---------------- row norms f32 (wave per row) ----------------
__global__ __launch_bounds__(256) void rownorm_k(const float* __restrict__ X,
                                                 float* __restrict__ nrm,
                                                 float* __restrict__ rinv, int D) {
  int w = threadIdx.x >> 6, l = threadIdx.x & 63;
  long row = (long)blockIdx.x * 4 + w;
  const float4* Xr = reinterpret_cast<const float4*>(X + row * D);
  float s = 0.f;
  for (int idx = l; idx < (D >> 2); idx += 64) {
    float4 v = Xr[idx];
    s += v.x * v.x + v.y * v.y + v.z * v.z + v.w * v.w;
  }
  s = wredsum(s);
  if (l == 0) {
    float n = sqrtf(s);
    nrm[row] = n;
    rinv[row] = 1.f / fmaxf(n, 1e-12f);
  }
}

// ---------------- row rinv of bf16 P (D=2048) ----------------
__global__ __launch_bounds__(256) void rownorm_b_k(const unsigned short* __restrict__ X,
                                                   float* __restrict__ rinv) {
  int w = threadIdx.x >> 6, l = threadIdx.x & 63;
  long row = (long)blockIdx.x * 4 + w;
  const ushort4* Xr = reinterpret_cast<const ushort4*>(X + row * 2048);
  float s = 0.f;
#pragma unroll
  for (int it = 0; it < 8; ++it) {
    ushort4 v = Xr[it * 64 + l];
    float a = b2f(v.x), b = b2f(v.y), c = b2f(v.z), d = b2f(v.w);
    s += a * a + b * b + c * c + d * d;
  }
  s = wredsum(s);
  if (l == 0) rinv[row] = 1.f / fmaxf(sqrtf(s), 1e-12f);
}

// ---------------- saliency softmax over N=512 ----------------
__global__ __launch_bounds__(256) void saliency_k(const float* __restrict__ nrm,
                                                  float* __restrict__ mu,
                                                  float* __restrict__ logmu) {
  __shared__ float sd[256];
  int b = blockIdx.x, t = threadIdx.x;
  float a = nrm[b * 512 + t], c = nrm[b * 512 + 256 + t];
  sd[t] = fmaxf(a, c);
  __syncthreads();
  for (int o = 128; o > 0; o >>= 1) { if (t < o) sd[t] = fmaxf(sd[t], sd[t + o]); __syncthreads(); }
  float M = sd[0];
  __syncthreads();
  float e1 = __expf(a - M), e2 = __expf(c - M);
  sd[t] = e1 + e2;
  __syncthreads();
  for (int o = 128; o > 0; o >>= 1) { if (t < o) sd[t] += sd[t + o]; __syncthreads(); }
  float S = sd[0];
  float m1 = e1 / S, m2 = e2 / S;
  mu[b * 512 + t] = m1;
  mu[b * 512 + 256 + t] = m2;
  logmu[b * 512 + t] = logf(m1 + 1e-8f);
  logmu[b * 512 + 256 + t] = logf(m2 + 1e-8f);
}

// ---------------- MFMA NT GEMM: C[b] = A[b] (Ma x K) @ B[b]^T (Nb-rows x K), bf16 in ----
// 128x128 tile, BK=32, 4 waves (2x2), wave tile 64x64 = 4x4 frags of 16x16x32.
// LDS [row][kblk] with kblk XOR-swizzled by (row>>1)&3 -> conflict-free ds_read_b128.
// EPI 0: Cf = 1 - acc*sa[i]*sb[j]          (cos distance, f32 out: Cs, M)
// EPI 1: Cb = bf16(1 - acc*sa[i]*sb[j])    (Ct)
// EPI 2: Cb = bf16(acc + bias[j])          (projection, b==0)
// EPI 3: Cb = bf16(acc)                    (T1 = Gnorm @ Ct)
// EPI 4: p += (Cs - acc)^2 * mu[i]*mu[j]; atomicAdd (struct loss, no store)
template <int EPI>
__global__ __launch_bounds__(256) void mfma_nt_k(
    const unsigned short* __restrict__ A, const unsigned short* __restrict__ Bm,
    float* __restrict__ Cf, unsigned short* __restrict__ Cb,
    const float* __restrict__ sa, const float* __restrict__ sb,
    const float* __restrict__ bias, const float* __restrict__ Csm,
    const float* __restrict__ muv, float* __restrict__ accp,
    int K, int Nb, long strA, long strB, long strC) {
  __shared__ int4 As4[512], Bs4[512];
  __shared__ float red[256];
  int b = blockIdx.z;
  const unsigned short* Ab = A + (long)b * strA;
  const unsigned short* Bb = Bm + (long)b * strB;
  int i0 = blockIdx.y * 128, j0 = blockIdx.x * 128;
  int t = threadIdx.x;
  int w = t >> 6, l = t & 63;
  int wi = w >> 1, wj = w & 1;
  int fr = l & 15, q = l >> 4;
  int srow = t >> 2, sslot = t & 3;

  f32x4 acc[4][4];
#pragma unroll
  for (int mi = 0; mi < 4; ++mi)
#pragma unroll
    for (int ni = 0; ni < 4; ++ni) acc[mi][ni] = f32x4{0.f, 0.f, 0.f, 0.f};

  for (int k0 = 0; k0 < K; k0 += 32) {
    __syncthreads();
    int r0 = srow, r1 = srow + 64;
    int4 a0 = *reinterpret_cast<const int4*>(Ab + (long)(i0 + r0) * K + k0 + sslot * 8);
    int4 a1 = *reinterpret_cast<const int4*>(Ab + (long)(i0 + r1) * K + k0 + sslot * 8);
    int4 b0 = *reinterpret_cast<const int4*>(Bb + (long)(j0 + r0) * K + k0 + sslot * 8);
    int4 b1 = *reinterpret_cast<const int4*>(Bb + (long)(j0 + r1) * K + k0 + sslot * 8);
    As4[r0 * 4 + (sslot ^ ((r0 >> 1) & 3))] = a0;
    As4[r1 * 4 + (sslot ^ ((r1 >> 1) & 3))] = a1;
    Bs4[r0 * 4 + (sslot ^ ((r0 >> 1) & 3))] = b0;
    Bs4[r1 * 4 + (sslot ^ ((r1 >> 1) & 3))] = b1;
    __syncthreads();
    short8 af[4], bfr[4];
#pragma unroll
    for (int mi = 0; mi < 4; ++mi) {
      int R = wi * 64 + mi * 16 + fr;
      af[mi] = *reinterpret_cast<const short8*>(&As4[R * 4 + (q ^ ((R >> 1) & 3))]);
    }
#pragma unroll
    for (int ni = 0; ni < 4; ++ni) {
      int R = wj * 64 + ni * 16 + fr;
      bfr[ni] = *reinterpret_cast<const short8*>(&Bs4[R * 4 + (q ^ ((R >> 1) & 3))]);
    }
#pragma unroll
    for (int mi = 0; mi < 4; ++mi)
#pragma unroll
      for (int ni = 0; ni < 4; ++ni)
        acc[mi][ni] = __builtin_amdgcn_mfma_f32_16x16x32_bf16(af[mi], bfr[ni], acc[mi][ni], 0, 0, 0);
  }

  // D layout: row = (l>>4)*4 + r, col = l&15
  int ib = i0 + wi * 64 + (q << 2);
  int jb = j0 + wj * 64 + fr;
  if (EPI == 0 || EPI == 1) {
#pragma unroll
    for (int mi = 0; mi < 4; ++mi)
#pragma unroll
      for (int r = 0; r < 4; ++r) {
        int i = ib + mi * 16 + r;
        float rsa = sa[b * 512 + i];
#pragma unroll
        for (int ni = 0; ni < 4; ++ni) {
          int j = jb + ni * 16;
          float val = 1.f - acc[mi][ni][r] * rsa * sb[b * 512 + j];
          if (EPI == 0) Cf[(long)b * strC + (long)i * Nb + j] = val;
          else Cb[(long)b * strC + (long)i * Nb + j] = f2b(val);
        }
      }
  } else if (EPI == 2) {
#pragma unroll
    for (int mi = 0; mi < 4; ++mi)
#pragma unroll
      for (int r = 0; r < 4; ++r) {
        int i = ib + mi * 16 + r;
#pragma unroll
        for (int ni = 0; ni < 4; ++ni) {
          int j = jb + ni * 16;
          Cb[(long)i * Nb + j] = f2b(acc[mi][ni][r] + bias[j]);
        }
      }
  } else if (EPI == 3) {
#pragma unroll
    for (int mi = 0; mi < 4; ++mi)
#pragma unroll
      for (int r = 0; r < 4; ++r) {
        int i = ib + mi * 16 + r;
#pragma unroll
        for (int ni = 0; ni < 4; ++ni)
          Cb[(long)b * strC + (long)i * Nb + jb + ni * 16] = f2b(acc[mi][ni][r]);
      }
  } else {
    float p = 0.f;
#pragma unroll
    for (int mi = 0; mi < 4; ++mi)
#pragma unroll
      for (int r = 0; r < 4; ++r) {
        int i = ib + mi * 16 + r;
        float mua = muv[b * 512 + i];
#pragma unroll
        for (int ni = 0; ni < 4; ++ni) {
          int j = jb + ni * 16;
          float d = Csm[(long)b * strC + (long)i * Nb + j] - acc[mi][ni][r];
          p += d * d * mua * muv[b * 512 + j];
        }
      }
    red[t] = p;
    __syncthreads();
    for (int o = 128; o > 0; o >>= 1) { if (t < o) red[t] += red[t + o]; __syncthreads(); }
    if (t == 0) atomicAdd(accp, red[0]);
  }
}

// ---------------- fused sinkhorn: u-update (row lse) + column partials, M read ONCE ----
// grid (8 ic, 32 b); block 256 = 4 waves x 16 rows each = 64 rows/block.
__global__ __launch_bounds__(256) void sink_uva_k(
    const float* __restrict__ Mm, const float* __restrict__ vv,
    const float* __restrict__ logmu, float* __restrict__ uu,
    float* __restrict__ pm, float* __restrict__ ps) {
  __shared__ float Lm[4][512], Ls[4][512];
  int b = blockIdx.y, ic = blockIdx.x;
  int t = threadIdx.x, w = t >> 6, l = t & 63;
  float vj[8], cm[8], cs[8];
#pragma unroll
  for (int jj = 0; jj < 8; ++jj) {
    vj[jj] = vv[b * 512 + jj * 64 + l];
    cm[jj] = -INFINITY;
    cs[jj] = 0.f;
  }
  for (int rr = 0; rr < 16; ++rr) {
    int i = ic * 64 + w * 16 + rr;
    const float* Mr = Mm + ((long)b * 512 + i) * 512;
    float mraw[8];
    float m = -INFINITY, s = 0.f;
#pragma unroll
    for (int jj = 0; jj < 8; ++jj) {
      mraw[jj] = -10.f * Mr[jj * 64 + l];
      float val = mraw[jj] + vj[jj];
      if (val > m) { s = s * __expf(m - val) + 1.f; m = val; } else s += __expf(val - m);
    }
#pragma unroll
    for (int o = 1; o < 64; o <<= 1) {
      float m2 = __shfl_xor(m, o), s2 = __shfl_xor(s, o);
      float nm = fmaxf(m, m2);
      s = s * __expf(m - nm) + s2 * __expf(m2 - nm);
      m = nm;
    }
    float ui = logmu[b * 512 + i] - (m + logf(s));
    if (l == 0) uu[b * 512 + i] = ui;
#pragma unroll
    for (int jj = 0; jj < 8; ++jj) {
      float cv = mraw[jj] + ui;
      if (cv > cm[jj]) { cs[jj] = cs[jj] * __expf(cm[jj] - cv) + 1.f; cm[jj] = cv; }
      else cs[jj] += __expf(cv - cm[jj]);
    }
  }
#pragma unroll
  for (int jj = 0; jj < 8; ++jj) { Lm[w][jj * 64 + l] = cm[jj]; Ls[w][jj * 64 + l] = cs[jj]; }
  __syncthreads();
#pragma unroll
  for (int jb = 0; jb < 2; ++jb) {
    int j = jb * 256 + t;
    float m = Lm[0][j], s = Ls[0][j];
#pragma unroll
    for (int w2 = 1; w2 < 4; ++w2) {
      float m2 = Lm[w2][j], s2 = Ls[w2][j];
      float nm = fmaxf(m, m2);
      s = s * __expf(m - nm) + s2 * __expf(m2 - nm);
      m = nm;
    }
    pm[((long)(b * 512 + j) << 3) + ic] = m;
    ps[((long)(b * 512 + j) << 3) + ic] = s;
  }
}

__global__ __launch_bounds__(256) void sink_vb_k(const float* __restrict__ pm,
                                                 const float* __restrict__ ps,
                                                 const float* __restrict__ lognu,
                                                 float* __restrict__ v) {
  int b = blockIdx.y;
  int j = blockIdx.x * 256 + threadIdx.x;
  float m = -INFINITY, s = 0.f;
#pragma unroll
  for (int ic = 0; ic < 8; ++ic) {
    float m2 = pm[((long)(b * 512 + j) << 3) + ic], s2 = ps[((long)(b * 512 + j) << 3) + ic];
    float nm = fmaxf(m, m2);
    s = s * __expf(m - nm) + s2 * __expf(m2 - nm);
    m = nm;
  }
  v[b * 512 + j] = lognu[b * 512 + j] - (m + logf(s));
}

// ---------------- Gamma_norm (bf16) + feat partials ----------------
__global__ __launch_bounds__(256) void gamma_k(const float* __restrict__ Mm,
                                               const float* __restrict__ u,
                                               const float* __restrict__ v,
                                               unsigned short* __restrict__ Gn,
                                               float* __restrict__ feat_row) {
  int b = blockIdx.y;
  int w = threadIdx.x >> 6, l = threadIdx.x & 63;
  int i = blockIdx.x * 4 + w;
  const float* Mr = Mm + ((long)b * 512 + i) * 512;
  unsigned short* Gr = Gn + ((long)b * 512 + i) * 512;
  float ui = u[b * 512 + i];
  float g[8];
  float rs = 0.f, fp = 0.f;
#pragma unroll
  for (int jj = 0; jj < 8; ++jj) {
    int j = jj * 64 + l;
    float mm = Mr[j];
    g[jj] = __expf(fmaf(-10.f, mm, ui + v[b * 512 + j]));
    rs += g[jj];
    fp = fmaf(mm, g[jj], fp);
  }
  rs = wredsum(rs);
  fp = wredsum(fp);
  float invr = 1.f / (rs + 1e-8f);
#pragma unroll
  for (int jj = 0; jj < 8; ++jj) Gr[jj * 64 + l] = f2b(g[jj] * invr);
  if (l == 0) feat_row[b * 512 + i] = fp;
}

__global__ __launch_bounds__(256) void reduce_sum_k(const float* __restrict__ x, int n,
                                                    float* __restrict__ out) {
  __shared__ float sd[256];
  int t = threadIdx.x;
  float s = 0.f;
  for (int i = t; i < n; i += 256) s += x[i];
  sd[t] = s;
  __syncthreads();
  for (int o = 128; o > 0; o >>= 1) { if (t < o) sd[t] += sd[t + o]; __syncthreads(); }
  if (t == 0) atomicAdd(out, sd[0]);
}

// ---------------- Contrastive (f32, tiny) ----------------
__global__ __launch_bounds__(256) void cnorm_k(const float* __restrict__ q,
                                               const float* __restrict__ p,
                                               float* __restrict__ rqp) {
  __shared__ float sd[3][256];
  int mat = blockIdx.x >> 5, row = blockIdx.x & 31, t = threadIdx.x;
  const float* X = (mat ? p : q) + row * 1024;
  float x0 = X[t], x1 = X[256 + t], x2 = X[512 + t], x3 = X[768 + t];
  sd[0][t] = x0 * x0;
  sd[1][t] = x1 * x1;
  sd[2][t] = x2 * x2 + x3 * x3;
  __syncthreads();
  for (int o = 128; o > 0; o >>= 1) {
    if (t < o) { sd[0][t] += sd[0][t + o]; sd[1][t] += sd[1][t + o]; sd[2][t] += sd[2][t + o]; }
    __syncthreads();
  }
  if (t == 0) {
    float c1 = sd[0][0], c2 = c1 + sd[1][0], c3 = c2 + sd[2][0];
    rqp[(mat * 32 + row) * 3 + 0] = 1.f / fmaxf(sqrtf(c1), 1e-12f);
    rqp[(mat * 32 + row) * 3 + 1] = 1.f / fmaxf(sqrtf(c2), 1e-12f);
    rqp[(mat * 32 + row) * 3 + 2] = 1.f / fmaxf(sqrtf(c3), 1e-12f);
  }
}

__global__ __launch_bounds__(256) void cscore_k(const float* __restrict__ q,
                                                const float* __restrict__ p,
                                                float* __restrict__ sc3) {
  int i = blockIdx.x;
  int w = threadIdx.x >> 6, l = threadIdx.x & 63;
  const float* qi = q + i * 1024;
  for (int j8 = 0; j8 < 8; ++j8) {
    int j = j8 * 4 + w;
    const float* pj = p + j * 1024;
    float s1 = 0.f, s2 = 0.f, s3 = 0.f;
#pragma unroll
    for (int it = 0; it < 4; ++it) { int e = it * 64 + l; s1 = fmaf(qi[e], pj[e], s1); }
#pragma unroll
    for (int it = 4; it < 8; ++it) { int e = it * 64 + l; s2 = fmaf(qi[e], pj[e], s2); }
#pragma unroll
    for (int it = 8; it < 16; ++it) { int e = it * 64 + l; s3 = fmaf(qi[e], pj[e], s3); }
    s1 = wredsum(s1); s2 = wredsum(s2); s3 = wredsum(s3);
    if (l == 0) {
      sc3[(0 * 32 + i) * 32 + j] = s1;
      sc3[(1 * 32 + i) * 32 + j] = s1 + s2;
      sc3[(2 * 32 + i) * 32 + j] = s1 + s2 + s3;
    }
  }
}

__global__ void closs_k(const float* __restrict__ sc3, const float* __restrict__ rqp,
                        float* __restrict__ acc) {
  int i = blockIdx.x, d = blockIdx.y, j = threadIdx.x;
  float sc = -INFINITY;
  if (j < 32)
    sc = sc3[(d * 32 + i) * 32 + j] * rqp[i * 3 + d] * rqp[(32 + j) * 3 + d] * (1.f / 0.07f);
  float mx = wredmax(sc);
  float e = (j < 32) ? __expf(sc - mx) : 0.f;
  float S = wredsum(e);
  float lse = mx + logf(S);
  float diag = __shfl(sc, i);
  if (j == 0) atomicAdd(acc, (lse - diag) * (1.f / 32.f));
}

__global__ void final_k(const float* __restrict__ acc, float* __restrict__ out) {
  float contr = acc[0];
  float lq = 0.5f * (acc[1] / 32.f) + 0.5f * (acc[2] / 32.f);
  float lp = 0.5f * (acc[3] / 32.f) + 0.5f * (acc[4] / 32.f);
  out[0] = contr + 0.5f * (lq + lp);
}

extern "C" void kernel_launch(void* const* d_in, const int* in_sizes, int n_in,
                              void* d_out, int out_size, void* d_ws, size_t ws_size,
                              hipStream_t stream) {
  const float* s_q_reps = (const float*)d_in[0];
  const float* s_p_reps = (const float*)d_in[1];
  const float* s_q_states = (const float*)d_in[2];
  const float* s_p_states = (const float*)d_in[3];
  const float* t_q_states = (const float*)d_in[4];
  const float* t_p_states = (const float*)d_in[5];
  const float* Wp = (const float*)d_in[6];
  const float* bp = (const float*)d_in[7];
  float* ws = (float*)d_ws;

  // float-unit offsets (total ~224 MB, < proven 237 MB footprint)
  unsigned short* WtB = (unsigned short*)(ws + 0);          // 2M bf16 = 1048576 f
  unsigned short* zsb = (unsigned short*)(ws + 1048576);    // 16.7M bf16 = 8388608 f
  float* Mm = ws + 1048576;                                 // aliases zsb (dead after Cs/proj)
  unsigned short* ztb = (unsigned short*)(ws + 9437184);    // 33.5M bf16 = 16777216 f
  unsigned short* Pb = (unsigned short*)(ws + 26214400);    // 33.5M bf16 = 16777216 f
  unsigned short* Gnb = (unsigned short*)(ws + 26214400);   // aliases Pb (dead after M)
  unsigned short* T1b = (unsigned short*)(ws + 30408704);   // aliases Pb upper half
  unsigned short* Ctb = (unsigned short*)(ws + 42991616);   // 8.4M bf16 = 4194304 f
  float* Cs = ws + 47185920;                                // 8388608 f
  float* sm = ws + 55574528;
  float* nrm_s = sm; sm += 16384;
  float* rinv_s = sm; sm += 16384;
  float* nrm_t = sm; sm += 16384;
  float* rinv_t = sm; sm += 16384;
  float* rinv_p = sm; sm += 16384;
  float* mu = sm; sm += 16384;
  float* logmu = sm; sm += 16384;
  float* nu = sm; sm += 16384;
  float* lognu = sm; sm += 16384;
  float* uu = sm; sm += 16384;
  float* vv = sm; sm += 16384;
  float* feat_row = sm; sm += 16384;
  float* pm = sm; sm += 131072;
  float* ps = sm; sm += 131072;
  float* sc3 = sm; sm += 3072;
  float* rqp = sm; sm += 192;
  float* acc = sm; sm += 16;

  hipMemsetAsync(acc, 0, 16 * sizeof(float), stream);

  // ---- contrastive ----
  cnorm_k<<<64, 256, 0, stream>>>(s_q_reps, s_p_reps, rqp);
  cscore_k<<<32, 256, 0, stream>>>(s_q_reps, s_p_reps, sc3);
  closs_k<<<dim3(32, 3), 64, 0, stream>>>(sc3, rqp, acc);

  // ---- W transpose to bf16 (once) ----
  wt_k<<<dim3(64, 32), 256, 0, stream>>>(Wp, WtB);

  for (int side = 0; side < 2; ++side) {
    const float* zs = side ? s_p_states : s_q_states;
    const float* zt = side ? t_p_states : t_q_states;
    float* featAcc = acc + 1 + side * 2;
    float* structAcc = acc + 2 + side * 2;

    cvt_k<<<16384, 256, 0, stream>>>(zs, zsb);
    cvt_k<<<32768, 256, 0, stream>>>(zt, ztb);
    rownorm_k<<<4096, 256, 0, stream>>>(zs, nrm_s, rinv_s, 1024);
    rownorm_k<<<4096, 256, 0, stream>>>(zt, nrm_t, rinv_t, 2048);
    saliency_k<<<32, 256, 0, stream>>>(nrm_s, mu, logmu);
    saliency_k<<<32, 256, 0, stream>>>(nrm_t, nu, lognu);

    // P = zs @ W + b (bf16 out), NT with Wt[2048][1024]
    mfma_nt_k<2><<<dim3(16, 128, 1), 256, 0, stream>>>(
        zsb, WtB, nullptr, Pb, nullptr, nullptr, bp, nullptr, nullptr, nullptr,
        1024, 2048, 0, 0, 0);
    rownorm_b_k<<<4096, 256, 0, stream>>>(Pb, rinv_p);

    // Cs (f32) — must precede M (Mm aliases zsb)
    mfma_nt_k<0><<<dim3(4, 4, 32), 256, 0, stream>>>(
        zsb, zsb, Cs, nullptr, rinv_s, rinv_s, nullptr, nullptr, nullptr, nullptr,
        1024, 512, 512L * 1024, 512L * 1024, 512L * 512);
    // Ct (bf16)
    mfma_nt_k<1><<<dim3(4, 4, 32), 256, 0, stream>>>(
        ztb, ztb, nullptr, Ctb, rinv_t, rinv_t, nullptr, nullptr, nullptr, nullptr,
        2048, 512, 512L * 2048, 512L * 2048, 512L * 512);
    // M (f32)
    mfma_nt_k<0><<<dim3(4, 4, 32), 256, 0, stream>>>(
        Pb, ztb, Mm, nullptr, rinv_p, rinv_t, nullptr, nullptr, nullptr, nullptr,
        2048, 512, 512L * 2048, 512L * 2048, 512L * 512);

    hipMemsetAsync(vv, 0, 16384 * sizeof(float), stream);
    for (int it = 0; it < 20; ++it) {
      sink_uva_k<<<dim3(8, 32), 256, 0, stream>>>(Mm, vv, logmu, uu, pm, ps);
      sink_vb_k<<<dim3(2, 32), 256, 0, stream>>>(pm, ps, lognu, vv);
    }
    gamma_k<<<dim3(128, 32), 256, 0, stream>>>(Mm, uu, vv, Gnb, feat_row);
    reduce_sum_k<<<1, 256, 0, stream>>>(feat_row, 16384, featAcc);

    // T1 = Gnorm @ Ct (Ct symmetric -> NT), bf16 out
    mfma_nt_k<3><<<dim3(4, 4, 32), 256, 0, stream>>>(
        Gnb, Ctb, nullptr, T1b, nullptr, nullptr, nullptr, nullptr, nullptr, nullptr,
        512, 512, 512L * 512, 512L * 512, 512L * 512);
    // struct: sum (Cs - T1@Gnorm^T)^2 * mu_i*mu_j
    mfma_nt_k<4><<<dim3(4, 4, 32), 256, 0, stream>>>(
        T1b, Gnb, nullptr, nullptr, nullptr, nullptr, nullptr, Cs, mu, structAcc,
        512, 512, 512L * 512, 512L * 512, 512L * 512);
  }

  final_k<<<1, 1, 0, stream>>>(acc, (float*)d_out);
}